// Round 7
// baseline (120.745 us; speedup 1.0000x reference)
//
#include <hip/hip_runtime.h>
#include <hip/hip_bf16.h>

#define D_DIM   256
#define N_TOT   4096
#define N_ANCH  256
#define NPART   64                    // partAll slots per row (32 col groups x 2 wave-cols)
#define K1  20.60992915555662f        // (1/0.07) * log2(e)
#define LN2 0.6931471805599453f
#define MAXNP    48                   // max anchors per label (19 labels, mean 13.5)

typedef __attribute__((ext_vector_type(8))) short bf16x8;
typedef __attribute__((ext_vector_type(4))) float f32x4;

#define MFMA(a, b, c) __builtin_amdgcn_mfma_f32_16x16x32_bf16((a), (b), (c), 0, 0, 0)

__device__ __forceinline__ ushort f2bf(float f) {
    union { float f; unsigned u; } a; a.f = f;
    unsigned u = a.u;
    u = (u + 0x7FFFu + ((u >> 16) & 1u)) >> 16;   // RNE
    return (ushort)u;
}

// ---------- kernel 0: fp32 -> bf16 convert; block 0: label setup + counter zero ----------
__global__ void __launch_bounds__(256) k_prep(const float* __restrict__ feats,
                                              const int* __restrict__ labels,
                                              ushort* __restrict__ xb,
                                              int* __restrict__ cntW,
                                              int* __restrict__ posRank,
                                              int* __restrict__ tileOff,
                                              int* __restrict__ ctrs) {
    int idx = blockIdx.x * 256 + threadIdx.x;
    int base = idx * 4;
    float4 v = *(const float4*)(feats + base);
    ushort4 o;
    o.x = f2bf(v.x); o.y = f2bf(v.y); o.z = f2bf(v.z); o.w = f2bf(v.w);
    *(ushort4*)(xb + base) = o;

    if (blockIdx.x == 0) {
        __shared__ int labS[N_ANCH];
        __shared__ int cntS[32];
        int t = threadIdx.x;
        if (t < 33) ctrs[t] = 0;          // zero completion counters (every call!)
        if (t < 32) cntS[t] = 0;
        labS[t] = labels[t];
        __syncthreads();
        atomicAdd(&cntS[labS[t]], 1);
        __syncthreads();
        int myLab = labS[t];
        int rank = 0, toff = 0;
        for (int b = 0; b < t; ++b) {
            int lb = labS[b];
            rank += (lb == myLab);
            toff += cntS[lb];
        }
        posRank[t] = rank;
        tileOff[t] = toff;
        if (t < 32) cntW[t] = cntS[t];
    }
}

// ---------- kernel 1: fused GEMM sweep + per-row-group positive pass + final ----------
// 1024 blocks (32 row groups g x 32 col groups s), 256 threads = 4 waves (2x2).
// Phase 1 (all blocks): 128x128 tile GEMM, S_all partials + positive-tile stores.
// Phase 2 (last block per g): softmax-log pass for g's 8 anchors (posBuf complete).
// Phase 3 (last winner): reduce 32 group sums -> out.
__global__ void __launch_bounds__(256, 2) k_mega(const ushort* __restrict__ xb,
                                                 const int* __restrict__ labels,
                                                 const int* __restrict__ posRank,
                                                 const int* __restrict__ tileOff,
                                                 const int* __restrict__ cntW,
                                                 float* __restrict__ partAll,
                                                 float* __restrict__ posBuf,
                                                 float* __restrict__ partOut,
                                                 int* __restrict__ ctrs,
                                                 float* __restrict__ out) {
    __shared__ __align__(16) char lds[65536];   // phase1: A[0,32K) B[32K,64K); phase2: tile cache
    __shared__ float shA[16][17];
    __shared__ float shB[16][17];
    __shared__ float nsSh[16], PSh[16];
    __shared__ int winS;

    const int g = blockIdx.x >> 5;              // row group (8 anchors = 128 rows)
    const int s = blockIdx.x & 31;              // col group
    const int tid = threadIdx.x;
    const int lane = tid & 63, wid = tid >> 6;
    const int lrow = lane & 15, khalf = lane >> 4;
    const int wr = wid >> 1, wc = wid & 1;      // wave sub-tile (wr*64, wc*64)

    // ================= phase 1: GEMM (identical to validated round-5 core) =================
    {
        const char* aSrc = (const char*)(xb + (size_t)g * 128 * D_DIM);
        const char* bSrc = (const char*)(xb + (size_t)s * 128 * D_DIM);

        uint32_t Lg[8], Lw[8];
#pragma unroll
        for (int o = 0; o < 8; ++o) {
            uint32_t L = (uint32_t)(tid * 16 + o * 4096);      // linear LDS byte
            Lg[o] = (L >> 8) * 512 + (L & 255);                // global byte in chunk
            Lw[o] = L ^ (((L >> 8) & 7u) << 4);                // swizzled LDS byte
        }

        bf16x8 stA[8], stB[8];
        auto loadch = [&](int kc) {
#pragma unroll
            for (int o = 0; o < 8; ++o) {
                stA[o] = *(const bf16x8*)(aSrc + Lg[o] + kc * 256);
                stB[o] = *(const bf16x8*)(bSrc + Lg[o] + kc * 256);
            }
        };
        auto writelds = [&]() {
#pragma unroll
            for (int o = 0; o < 8; ++o) {
                *(bf16x8*)(lds + Lw[o])         = stA[o];
                *(bf16x8*)(lds + 32768 + Lw[o]) = stB[o];
            }
        };

        f32x4 acc[4][4];
#pragma unroll
        for (int m = 0; m < 4; ++m)
#pragma unroll
            for (int n = 0; n < 4; ++n)
                acc[m][n] = (f32x4){0.f, 0.f, 0.f, 0.f};

        const uint32_t swz = (uint32_t)((lrow & 7) << 4);
        auto compute = [&]() {
#pragma unroll
            for (int ks = 0; ks < 4; ++ks) {
                bf16x8 af[4], bfr[4];
#pragma unroll
                for (int m = 0; m < 4; ++m) {
                    uint32_t row = (uint32_t)(wr * 64 + m * 16 + lrow);
                    af[m] = *(const bf16x8*)(lds + ((row * 256 + ks * 64 + khalf * 16) ^ swz));
                }
#pragma unroll
                for (int n = 0; n < 4; ++n) {
                    uint32_t row = (uint32_t)(wc * 64 + n * 16 + lrow);
                    bfr[n] = *(const bf16x8*)(lds + 32768 + ((row * 256 + ks * 64 + khalf * 16) ^ swz));
                }
#pragma unroll
                for (int m = 0; m < 4; ++m)
#pragma unroll
                    for (int n = 0; n < 4; ++n)
                        acc[m][n] = MFMA(af[m], bfr[n], acc[m][n]);
            }
        };

        loadch(0);
        writelds();
        __syncthreads();        // chunk 0 ready
        loadch(1);              // prefetch chunk 1 (hides under compute)
        compute();
        __syncthreads();        // all reads of chunk 0 done
        writelds();
        __syncthreads();        // chunk 1 ready
        compute();

        // ---- epilogue: exp2 row sums + positive-tile stores ----
        const int raBase = g * 8 + wr * 4, caBase = s * 8 + wc * 4;
        int labR[4], offR[4], labC[4], rankC[4];
#pragma unroll
        for (int m = 0; m < 4; ++m) {
            labR[m] = labels[raBase + m];
            offR[m] = tileOff[raBase + m];
        }
#pragma unroll
        for (int n = 0; n < 4; ++n) {
            labC[n] = labels[caBase + n];
            rankC[n] = posRank[caBase + n];
        }

        float aAll[4][4];
#pragma unroll
        for (int m = 0; m < 4; ++m)
#pragma unroll
            for (int i = 0; i < 4; ++i) aAll[m][i] = 0.f;

#pragma unroll
        for (int m = 0; m < 4; ++m) {
#pragma unroll
            for (int n = 0; n < 4; ++n) {
                f32x4 c = acc[m][n];
#pragma unroll
                for (int i = 0; i < 4; ++i)
                    aAll[m][i] += exp2f(__builtin_fmaf(c[i], K1, -K1));
                if (labR[m] == labC[n])    // wave-uniform: store raw scores for phase 2
                    *(f32x4*)(posBuf + (size_t)(offR[m] + rankC[n]) * 256 + lane * 4) = c;
            }
        }

#pragma unroll
        for (int msk = 1; msk < 16; msk <<= 1)
#pragma unroll
            for (int m = 0; m < 4; ++m)
#pragma unroll
                for (int i = 0; i < 4; ++i)
                    aAll[m][i] += __shfl_xor(aAll[m][i], msk, 64);

        if (lrow == 0) {
#pragma unroll
            for (int m = 0; m < 4; ++m)
#pragma unroll
                for (int i = 0; i < 4; ++i) {
                    int row = g * 128 + wr * 64 + m * 16 + khalf * 4 + i;
                    partAll[row * NPART + s * 2 + wc] = aAll[m][i];
                }
        }
    }

    // ================= row-group completion: last of 32 blocks proceeds =================
    __syncthreads();                       // all block writes issued & drained (vmcnt 0)
    if (tid == 0) {
        __threadfence();                   // release: flush our XCD L2
        winS = (atomicAdd(&ctrs[g], 1) == 31);
    }
    __syncthreads();
    if (!winS) return;
    __threadfence();                       // acquire: invalidate stale lines

    // ================= phase 2: positive pass for g's 8 anchors =================
    float* tile = (float*)lds;             // reuse GEMM LDS (needs 48 KB)
    const int l = tid >> 2, ii = tid & 3;
    const int r   = (l >> 4) * 4 + ii;     // row within 16x16 tile
    const int col = l & 15;
    float myAcc = 0.f;                     // valid on tid<16 only

    for (int aIdx = 0; aIdx < 8; ++aIdx) {
        int rt = g * 8 + aIdx;
        int np       = cntW[labels[rt]];
        int off      = tileOff[rt];
        int selfRank = posRank[rt];
        __syncthreads();                   // tile/shA/shB free from previous anchor

        float sE = 0.f, sP = 0.f;
        const float* src = posBuf + (size_t)off * 256 + tid;
        for (int j = 0; j < np; ++j) {
            float c = src[j * 256];
            tile[j * 256 + tid] = c;
            float l2 = __builtin_fmaf(c, K1, -K1);
            sE += exp2f(l2);
            bool diag = (j == selfRank) & (col == r);
            sP += diag ? 0.f : l2;
        }
        shA[r][col] = sE;
        shB[r][col] = sP;
        __syncthreads();
        if (tid < 16) {
            float e = 0.f, p = 0.f;
#pragma unroll
            for (int cc = 0; cc < 16; ++cc) { e += shA[tid][cc]; p += shB[tid][cc]; }
            const float* pa = partAll + (size_t)(rt * 16 + tid) * NPART;
            float sall = 0.f;
#pragma unroll
            for (int q = 0; q < 16; ++q) {
                float4 v = *(const float4*)(pa + q * 4);
                sall += v.x + v.y + v.z + v.w;
            }
            nsSh[tid] = sall - e;          // negative-pair exp sum
            PSh[tid]  = p;
        }
        __syncthreads();

        float nsv = nsSh[r];
        float sL = 0.f;
        for (int j = 0; j < np; ++j) {
            float c  = tile[j * 256 + tid];
            float l2 = __builtin_fmaf(c, K1, -K1);
            float lg = __log2f(exp2f(l2) + nsv);
            bool diag = (j == selfRank) & (col == r);
            sL += diag ? 0.f : lg;
        }
        __syncthreads();
        shA[r][col] = sL;
        __syncthreads();
        if (tid < 16) {
            float L = 0.f;
#pragma unroll
            for (int cc = 0; cc < 16; ++cc) L += shA[tid][cc];
            myAcc += (PSh[tid] - L) / (float)(16 * np - 1);
        }
    }

    // group sum -> partOut[g]
    __syncthreads();
    if (tid < 16) shA[0][tid] = myAcc;
    __syncthreads();
    if (tid == 0) {
        float gs = 0.f;
#pragma unroll
        for (int q = 0; q < 16; ++q) gs += shA[0][q];
        partOut[g] = gs;
    }

    // ================= phase 3: last winner reduces 32 group sums =================
    __syncthreads();
    if (tid == 0) {
        __threadfence();                   // release partOut[g]
        winS = (atomicAdd(&ctrs[32], 1) == 31);
    }
    __syncthreads();
    if (!winS) return;
    __threadfence();                       // acquire

    if (tid < 64) {
        float v = (tid < 32) ? partOut[tid] : 0.f;
#pragma unroll
        for (int m = 1; m <= 16; m <<= 1) v += __shfl_xor(v, m, 64);
        if (tid == 0) out[0] = -v * (LN2 / (float)N_TOT);
    }
}

extern "C" void kernel_launch(void* const* d_in, const int* in_sizes, int n_in,
                              void* d_out, int out_size, void* d_ws, size_t ws_size,
                              hipStream_t stream) {
    const float* feats  = (const float*)d_in[0];
    const int*   labels = (const int*)d_in[1];
    float* out = (float*)d_out;

    char* ws = (char*)d_ws;
    ushort* xb      = (ushort*)ws;                                  // 2 MB
    float*  partAll = (float*)(ws + (2u << 20));                    // 1 MB (4096*64 f32)
    float*  posBuf  = (float*)(ws + (3u << 20));                    // 8 MB
    char*   meta    = ws + (11u << 20);
    int*    cntW    = (int*)meta;                                   // 32 ints
    int*    posRank = (int*)(meta + 128);                           // 256 ints
    int*    tileOff = (int*)(meta + 128 + 1024);                    // 256 ints
    float*  partOut = (float*)(meta + 128 + 2048);                  // 32 floats
    int*    ctrs    = (int*)(meta + 128 + 2048 + 256);              // 33 ints

    k_prep<<<1024, 256, 0, stream>>>(feats, labels, xb, cntW, posRank, tileOff, ctrs);
    k_mega<<<1024, 256, 0, stream>>>(xb, labels, posRank, tileOff, cntW,
                                     partAll, posBuf, partOut, ctrs, out);
}

// Round 8
// 40.634 us; speedup vs baseline: 2.9715x; 2.9715x over previous
//
#include <hip/hip_runtime.h>
#include <hip/hip_bf16.h>

#define D_DIM   256
#define N_TOT   4096
#define N_ANCH  256
#define NPART   64                    // partAll slots per row (32 col groups x 2 wave-cols)
#define K1  20.60992915555662f        // (1/0.07) * log2(e)
#define LN2 0.6931471805599453f
#define MAXNP    48                   // max anchors per label (19 labels, mean 13.5)

typedef __attribute__((ext_vector_type(8))) short bf16x8;
typedef __attribute__((ext_vector_type(4))) float f32x4;

#define MFMA(a, b, c) __builtin_amdgcn_mfma_f32_16x16x32_bf16((a), (b), (c), 0, 0, 0)

__device__ __forceinline__ ushort f2bf(float f) {
    union { float f; unsigned u; } a; a.f = f;
    unsigned u = a.u;
    u = (u + 0x7FFFu + ((u >> 16) & 1u)) >> 16;   // RNE
    return (ushort)u;
}

// ---------- kernel 0: fp32 -> bf16 convert; block 0: label setup + counter zero ----------
__global__ void __launch_bounds__(256) k_prep(const float* __restrict__ feats,
                                              const int* __restrict__ labels,
                                              ushort* __restrict__ xb,
                                              int* __restrict__ cntW,
                                              int* __restrict__ posRank,
                                              int* __restrict__ tileOff,
                                              int* __restrict__ ctrs) {
    int idx = blockIdx.x * 256 + threadIdx.x;
    int base = idx * 4;
    float4 v = *(const float4*)(feats + base);
    ushort4 o;
    o.x = f2bf(v.x); o.y = f2bf(v.y); o.z = f2bf(v.z); o.w = f2bf(v.w);
    *(ushort4*)(xb + base) = o;

    if (blockIdx.x == 0) {
        __shared__ int labS[N_ANCH];
        __shared__ int cntS[32];
        int t = threadIdx.x;
        if (t < 4) ctrs[t] = 0;           // zero completion counters (every call!)
        if (t < 32) cntS[t] = 0;
        labS[t] = labels[t];
        __syncthreads();
        atomicAdd(&cntS[labS[t]], 1);
        __syncthreads();
        int myLab = labS[t];
        int rank = 0, toff = 0;
        for (int b = 0; b < t; ++b) {
            int lb = labS[b];
            rank += (lb == myLab);
            toff += cntS[lb];
        }
        posRank[t] = rank;
        tileOff[t] = toff;
        if (t < 32) cntW[t] = cntS[t];
    }
}

// ---------- kernel 1: 128x128-tile fused GEMM sweep (BK=64, 32 KB LDS) ----------
// 1024 blocks (32 row groups x 32 col groups), 256 threads = 4 waves (2x2).
// Each wave: 64x64 output = 4x4 fragments. K=256 in four BK=64 chunks through
// one 32 KB swizzled LDS buffer (A 16K + B 16K); reg-staged prefetch of the
// next chunk overlaps compute. 32 KB LDS -> 3-4 blocks/CU (vs 2 at 64 KB).
__global__ void __launch_bounds__(256, 3) k_pass1(const ushort* __restrict__ xb,
                                                  const int* __restrict__ labels,
                                                  const int* __restrict__ posRank,
                                                  const int* __restrict__ tileOff,
                                                  float* __restrict__ partAll,
                                                  float* __restrict__ posBuf) {
    __shared__ __align__(16) char lds[32768];   // A: [0,16K), B: [16K,32K)

    const int g = blockIdx.x >> 5;              // row group (8 anchors = 128 rows)
    const int s = blockIdx.x & 31;              // col group
    const int tid = threadIdx.x;
    const int lane = tid & 63, wid = tid >> 6;
    const int lrow = lane & 15, khalf = lane >> 4;
    const int wr = wid >> 1, wc = wid & 1;      // wave sub-tile (wr*64, wc*64)

    const char* aSrc = (const char*)(xb + (size_t)g * 128 * D_DIM);
    const char* bSrc = (const char*)(xb + (size_t)s * 128 * D_DIM);

    // staging address decode: per chunk, per operand: 4 x 16B per thread.
    // LDS chunk layout: 128 rows x 128 B (BK=64 bf16), row = L>>7.
    uint32_t Lg[4], Lw[4];
#pragma unroll
    for (int o = 0; o < 4; ++o) {
        uint32_t L = (uint32_t)(tid * 16 + o * 4096);      // linear chunk byte
        Lg[o] = (L >> 7) * 512 + (L & 127);                // global byte (row*512 + colb)
        Lw[o] = L ^ (((L >> 7) & 7u) << 4);                // swizzled LDS byte
    }

    bf16x8 stA[4], stB[4];
    auto loadch = [&](int kc) {
#pragma unroll
        for (int o = 0; o < 4; ++o) {
            stA[o] = *(const bf16x8*)(aSrc + Lg[o] + kc * 128);
            stB[o] = *(const bf16x8*)(bSrc + Lg[o] + kc * 128);
        }
    };
    auto writelds = [&]() {
#pragma unroll
        for (int o = 0; o < 4; ++o) {
            *(bf16x8*)(lds + Lw[o])         = stA[o];
            *(bf16x8*)(lds + 16384 + Lw[o]) = stB[o];
        }
    };

    f32x4 acc[4][4];
#pragma unroll
    for (int m = 0; m < 4; ++m)
#pragma unroll
        for (int n = 0; n < 4; ++n)
            acc[m][n] = (f32x4){0.f, 0.f, 0.f, 0.f};

    const uint32_t swz = (uint32_t)((lrow & 7) << 4);
    auto compute = [&]() {
#pragma unroll
        for (int ks = 0; ks < 2; ++ks) {           // two 32-k slices per chunk
            bf16x8 af[4], bfr[4];
#pragma unroll
            for (int m = 0; m < 4; ++m) {
                uint32_t row = (uint32_t)(wr * 64 + m * 16 + lrow);
                af[m] = *(const bf16x8*)(lds + ((row * 128 + ks * 64 + khalf * 16) ^ swz));
            }
#pragma unroll
            for (int n = 0; n < 4; ++n) {
                uint32_t row = (uint32_t)(wc * 64 + n * 16 + lrow);
                bfr[n] = *(const bf16x8*)(lds + 16384 + ((row * 128 + ks * 64 + khalf * 16) ^ swz));
            }
#pragma unroll
            for (int m = 0; m < 4; ++m)
#pragma unroll
                for (int n = 0; n < 4; ++n)
                    acc[m][n] = MFMA(af[m], bfr[n], acc[m][n]);
        }
    };

    loadch(0);
    writelds();
    __syncthreads();                   // chunk 0 ready
    for (int kc = 0; kc < 4; ++kc) {
        if (kc < 3) loadch(kc + 1);    // prefetch next chunk (overlaps compute)
        compute();
        if (kc < 3) {
            __syncthreads();           // all reads of chunk kc done
            writelds();
            __syncthreads();           // chunk kc+1 ready
        }
    }

    // ---- epilogue: exp2 row sums + positive-tile stores ----
    const int raBase = g * 8 + wr * 4, caBase = s * 8 + wc * 4;
    int labR[4], offR[4], labC[4], rankC[4];
#pragma unroll
    for (int m = 0; m < 4; ++m) {
        labR[m] = labels[raBase + m];
        offR[m] = tileOff[raBase + m];
    }
#pragma unroll
    for (int n = 0; n < 4; ++n) {
        labC[n] = labels[caBase + n];
        rankC[n] = posRank[caBase + n];
    }

    float aAll[4][4];       // [row-frag m][i]
#pragma unroll
    for (int m = 0; m < 4; ++m)
#pragma unroll
        for (int i = 0; i < 4; ++i) aAll[m][i] = 0.f;

#pragma unroll
    for (int m = 0; m < 4; ++m) {
#pragma unroll
        for (int n = 0; n < 4; ++n) {
            f32x4 c = acc[m][n];
#pragma unroll
            for (int i = 0; i < 4; ++i)
                aAll[m][i] += exp2f(__builtin_fmaf(c[i], K1, -K1));
            if (labR[m] == labC[n])    // wave-uniform: store raw scores for passB
                *(f32x4*)(posBuf + (size_t)(offR[m] + rankC[n]) * 256 + lane * 4) = c;
        }
    }

#pragma unroll
    for (int msk = 1; msk < 16; msk <<= 1)
#pragma unroll
        for (int m = 0; m < 4; ++m)
#pragma unroll
            for (int i = 0; i < 4; ++i)
                aAll[m][i] += __shfl_xor(aAll[m][i], msk, 64);

    if (lrow == 0) {
#pragma unroll
        for (int m = 0; m < 4; ++m)
#pragma unroll
            for (int i = 0; i < 4; ++i) {
                int row = g * 128 + wr * 64 + m * 16 + khalf * 4 + i;
                partAll[row * NPART + s * 2 + wc] = aAll[m][i];
            }
    }
}

// ---------- kernel 2: elementwise positive pass + fused final reduction ----------
__global__ void __launch_bounds__(256) k_passB(const float* __restrict__ posBuf,
                                               const int* __restrict__ labels,
                                               const int* __restrict__ cntW,
                                               const int* __restrict__ posRank,
                                               const int* __restrict__ tileOff,
                                               const float* __restrict__ partAll,
                                               float* __restrict__ partOut,
                                               int* __restrict__ ctrs,
                                               float* __restrict__ out) {
    int rt  = blockIdx.x;
    int tid = threadIdx.x;
    int l = tid >> 2, i = tid & 3;
    int r   = (l >> 4) * 4 + i;        // row within tile (fixed per thread)
    int col = l & 15;

    int np       = cntW[labels[rt]];
    int off      = tileOff[rt];
    int selfRank = posRank[rt];

    __shared__ float tile[MAXNP * 256];
    __shared__ float shA[16][17];
    __shared__ float shB[16][17];
    __shared__ float nsSh[16], PSh[16];
    __shared__ int winS;
    __shared__ float red[256];

    float sE = 0.f, sP = 0.f;
    const float* src = posBuf + (size_t)off * 256 + tid;
    for (int j = 0; j < np; ++j) {
        float c = src[j * 256];
        tile[j * 256 + tid] = c;
        float l2 = __builtin_fmaf(c, K1, -K1);
        sE += exp2f(l2);
        bool diag = (j == selfRank) & (col == r);
        sP += diag ? 0.f : l2;
    }
    shA[r][col] = sE;
    shB[r][col] = sP;
    __syncthreads();
    if (tid < 16) {
        float e = 0.f, p = 0.f;
#pragma unroll
        for (int cc = 0; cc < 16; ++cc) { e += shA[tid][cc]; p += shB[tid][cc]; }
        const float* pa = partAll + (size_t)(rt * 16 + tid) * NPART;
        float sall = 0.f;
#pragma unroll
        for (int q = 0; q < 16; ++q) {
            float4 v = *(const float4*)(pa + q * 4);
            sall += v.x + v.y + v.z + v.w;
        }
        nsSh[tid] = sall - e;          // negative-pair exp sum
        PSh[tid]  = p;
    }
    __syncthreads();

    float nsv = nsSh[r];
    float sL = 0.f;
    for (int j = 0; j < np; ++j) {
        float c  = tile[j * 256 + tid];
        float l2 = __builtin_fmaf(c, K1, -K1);
        float lg = __log2f(exp2f(l2) + nsv);
        bool diag = (j == selfRank) & (col == r);
        sL += diag ? 0.f : lg;
    }
    __syncthreads();
    shA[r][col] = sL;
    __syncthreads();
    if (tid < 16) {
        float L = 0.f;
#pragma unroll
        for (int cc = 0; cc < 16; ++cc) L += shA[tid][cc];
        float npRow = (float)(16 * np - 1);
        shB[0][tid] = (PSh[tid] - L) / npRow;
    }
    __syncthreads();
    if (tid == 0) {
        float sx = 0.f;
#pragma unroll
        for (int q = 0; q < 16; ++q) sx += shB[0][q];
        partOut[rt] = sx;
    }

    // ---- fused final: last of the 256 blocks reduces partOut -> out ----
    __syncthreads();
    if (tid == 0) {
        __threadfence();               // release partOut[rt]
        winS = (atomicAdd(&ctrs[0], 1) == N_ANCH - 1);
    }
    __syncthreads();
    if (!winS) return;
    __threadfence();                   // acquire all partOut

    red[tid] = partOut[tid];
    __syncthreads();
    for (int o2 = 128; o2; o2 >>= 1) {
        if (tid < o2) red[tid] += red[tid + o2];
        __syncthreads();
    }
    if (tid == 0) out[0] = -red[0] * (LN2 / (float)N_TOT);
}

extern "C" void kernel_launch(void* const* d_in, const int* in_sizes, int n_in,
                              void* d_out, int out_size, void* d_ws, size_t ws_size,
                              hipStream_t stream) {
    const float* feats  = (const float*)d_in[0];
    const int*   labels = (const int*)d_in[1];
    float* out = (float*)d_out;

    char* ws = (char*)d_ws;
    ushort* xb      = (ushort*)ws;                                  // 2 MB
    float*  partAll = (float*)(ws + (2u << 20));                    // 1 MB (4096*64 f32)
    float*  posBuf  = (float*)(ws + (3u << 20));                    // 8 MB
    char*   meta    = ws + (11u << 20);
    int*    cntW    = (int*)meta;                                   // 32 ints
    int*    posRank = (int*)(meta + 128);                           // 256 ints
    int*    tileOff = (int*)(meta + 128 + 1024);                    // 256 ints
    float*  partOut = (float*)(meta + 128 + 2048);                  // 256 floats
    int*    ctrs    = (int*)(meta + 128 + 2048 + 1024);             // 4 ints

    k_prep <<<1024, 256, 0, stream>>>(feats, labels, xb, cntW, posRank, tileOff, ctrs);
    k_pass1<<<1024, 256, 0, stream>>>(xb, labels, posRank, tileOff, partAll, posBuf);
    k_passB<<<N_ANCH, 256, 0, stream>>>(posBuf, labels, cntW, posRank, tileOff,
                                        partAll, partOut, ctrs, out);
}

// Round 9
// 40.441 us; speedup vs baseline: 2.9857x; 1.0048x over previous
//
#include <hip/hip_runtime.h>
#include <hip/hip_bf16.h>

#define D_DIM   256
#define N_TOT   4096
#define N_ANCH  256
#define NPART   64                    // partAll slots per row (32 col groups x 2 wave-cols)
#define K1  20.60992915555662f        // (1/0.07) * log2(e)
#define LN2 0.6931471805599453f
#define MAXNP    48                   // max anchors per label (19 labels, mean 13.5)

typedef __attribute__((ext_vector_type(8))) short bf16x8;
typedef __attribute__((ext_vector_type(4))) float f32x4;

#define MFMA(a, b, c) __builtin_amdgcn_mfma_f32_16x16x32_bf16((a), (b), (c), 0, 0, 0)

__device__ __forceinline__ ushort f2bf(float f) {
    union { float f; unsigned u; } a; a.f = f;
    unsigned u = a.u;
    u = (u + 0x7FFFu + ((u >> 16) & 1u)) >> 16;   // RNE
    return (ushort)u;
}

// ---------- kernel 0: fp32 -> bf16 convert (8 elems/thread); block 0: label setup ----------
__global__ void __launch_bounds__(256) k_prep(const float* __restrict__ feats,
                                              const int* __restrict__ labels,
                                              ushort* __restrict__ xb,
                                              int* __restrict__ cntW,
                                              int* __restrict__ posRank,
                                              int* __restrict__ tileOff,
                                              int* __restrict__ ctrs) {
    int idx = blockIdx.x * 256 + threadIdx.x;     // 512 blocks
    int base = idx * 8;
    float4 v0 = *(const float4*)(feats + base);
    float4 v1 = *(const float4*)(feats + base + 4);
    ushort o[8];
    o[0] = f2bf(v0.x); o[1] = f2bf(v0.y); o[2] = f2bf(v0.z); o[3] = f2bf(v0.w);
    o[4] = f2bf(v1.x); o[5] = f2bf(v1.y); o[6] = f2bf(v1.z); o[7] = f2bf(v1.w);
    *(ushort4*)(xb + base)     = *(ushort4*)&o[0];
    *(ushort4*)(xb + base + 4) = *(ushort4*)&o[4];

    if (blockIdx.x == 0) {
        __shared__ int labS[N_ANCH];
        __shared__ int cntS[32];
        int t = threadIdx.x;
        if (t < 4) ctrs[t] = 0;           // zero completion counters (every call!)
        if (t < 32) cntS[t] = 0;
        labS[t] = labels[t];
        __syncthreads();
        atomicAdd(&cntS[labS[t]], 1);
        __syncthreads();
        int myLab = labS[t];
        int rank = 0, toff = 0;
        for (int b = 0; b < t; ++b) {
            int lb = labS[b];
            rank += (lb == myLab);
            toff += cntS[lb];
        }
        posRank[t] = rank;
        tileOff[t] = toff;
        if (t < 32) cntW[t] = cntS[t];
    }
}

// ---------- kernel 1: 128x128-tile fused GEMM sweep (round-6 validated core) ----------
// 1024 blocks (32 row groups x 32 col groups), 256 threads = 4 waves (2x2).
// Each wave: 64x64 output = 4x4 fragments. K=256 in two BK=128 chunks
// through one 64 KB swizzled LDS buffer; reg-staged prefetch overlaps compute.
__global__ void __launch_bounds__(256, 2) k_pass1(const ushort* __restrict__ xb,
                                                  const int* __restrict__ labels,
                                                  const int* __restrict__ posRank,
                                                  const int* __restrict__ tileOff,
                                                  float* __restrict__ partAll,
                                                  float* __restrict__ posBuf) {
    __shared__ __align__(16) char lds[65536];   // A: [0,32K), B: [32K,64K)

    const int g = blockIdx.x >> 5;              // row group (8 anchors = 128 rows)
    const int s = blockIdx.x & 31;              // col group
    const int tid = threadIdx.x;
    const int lane = tid & 63, wid = tid >> 6;
    const int lrow = lane & 15, khalf = lane >> 4;
    const int wr = wid >> 1, wc = wid & 1;      // wave sub-tile (wr*64, wc*64)

    const char* aSrc = (const char*)(xb + (size_t)g * 128 * D_DIM);
    const char* bSrc = (const char*)(xb + (size_t)s * 128 * D_DIM);

    // staging address decode (8 x 16B per thread per operand per chunk)
    uint32_t Lg[8], Lw[8];
#pragma unroll
    for (int o = 0; o < 8; ++o) {
        uint32_t L = (uint32_t)(tid * 16 + o * 4096);      // linear LDS byte
        Lg[o] = (L >> 8) * 512 + (L & 255);                // global byte in chunk
        Lw[o] = L ^ (((L >> 8) & 7u) << 4);                // swizzled LDS byte
    }

    bf16x8 stA[8], stB[8];
    auto loadch = [&](int kc) {
#pragma unroll
        for (int o = 0; o < 8; ++o) {
            stA[o] = *(const bf16x8*)(aSrc + Lg[o] + kc * 256);
            stB[o] = *(const bf16x8*)(bSrc + Lg[o] + kc * 256);
        }
    };
    auto writelds = [&]() {
#pragma unroll
        for (int o = 0; o < 8; ++o) {
            *(bf16x8*)(lds + Lw[o])         = stA[o];
            *(bf16x8*)(lds + 32768 + Lw[o]) = stB[o];
        }
    };

    f32x4 acc[4][4];
#pragma unroll
    for (int m = 0; m < 4; ++m)
#pragma unroll
        for (int n = 0; n < 4; ++n)
            acc[m][n] = (f32x4){0.f, 0.f, 0.f, 0.f};

    const uint32_t swz = (uint32_t)((lrow & 7) << 4);
    auto compute = [&]() {
#pragma unroll
        for (int ks = 0; ks < 4; ++ks) {
            bf16x8 af[4], bfr[4];
#pragma unroll
            for (int m = 0; m < 4; ++m) {
                uint32_t row = (uint32_t)(wr * 64 + m * 16 + lrow);
                af[m] = *(const bf16x8*)(lds + ((row * 256 + ks * 64 + khalf * 16) ^ swz));
            }
#pragma unroll
            for (int n = 0; n < 4; ++n) {
                uint32_t row = (uint32_t)(wc * 64 + n * 16 + lrow);
                bfr[n] = *(const bf16x8*)(lds + 32768 + ((row * 256 + ks * 64 + khalf * 16) ^ swz));
            }
#pragma unroll
            for (int m = 0; m < 4; ++m)
#pragma unroll
                for (int n = 0; n < 4; ++n)
                    acc[m][n] = MFMA(af[m], bfr[n], acc[m][n]);
        }
    };

    loadch(0);
    writelds();
    __syncthreads();        // chunk 0 ready
    loadch(1);              // prefetch chunk 1 (hides under compute)
    compute();
    __syncthreads();        // all reads of chunk 0 done
    writelds();
    __syncthreads();        // chunk 1 ready
    compute();

    // ---- epilogue: exp2 row sums + positive-tile stores ----
    const int raBase = g * 8 + wr * 4, caBase = s * 8 + wc * 4;
    int labR[4], offR[4], labC[4], rankC[4];
#pragma unroll
    for (int m = 0; m < 4; ++m) {
        labR[m] = labels[raBase + m];
        offR[m] = tileOff[raBase + m];
    }
#pragma unroll
    for (int n = 0; n < 4; ++n) {
        labC[n] = labels[caBase + n];
        rankC[n] = posRank[caBase + n];
    }

    float aAll[4][4];       // [row-frag m][i]
#pragma unroll
    for (int m = 0; m < 4; ++m)
#pragma unroll
        for (int i = 0; i < 4; ++i) aAll[m][i] = 0.f;

#pragma unroll
    for (int m = 0; m < 4; ++m) {
#pragma unroll
        for (int n = 0; n < 4; ++n) {
            f32x4 c = acc[m][n];
#pragma unroll
            for (int i = 0; i < 4; ++i)
                aAll[m][i] += exp2f(__builtin_fmaf(c[i], K1, -K1));
            if (labR[m] == labC[n])    // wave-uniform: store raw scores for passB
                *(f32x4*)(posBuf + (size_t)(offR[m] + rankC[n]) * 256 + lane * 4) = c;
        }
    }

#pragma unroll
    for (int msk = 1; msk < 16; msk <<= 1)
#pragma unroll
        for (int m = 0; m < 4; ++m)
#pragma unroll
            for (int i = 0; i < 4; ++i)
                aAll[m][i] += __shfl_xor(aAll[m][i], msk, 64);

    if (lrow == 0) {
#pragma unroll
        for (int m = 0; m < 4; ++m)
#pragma unroll
            for (int i = 0; i < 4; ++i) {
                int row = g * 128 + wr * 64 + m * 16 + khalf * 4 + i;
                partAll[row * NPART + s * 2 + wc] = aAll[m][i];
            }
    }
}

// ---------- kernel 2: elementwise positive pass + fused final reduction ----------
__global__ void __launch_bounds__(256) k_passB(const float* __restrict__ posBuf,
                                               const int* __restrict__ labels,
                                               const int* __restrict__ cntW,
                                               const int* __restrict__ posRank,
                                               const int* __restrict__ tileOff,
                                               const float* __restrict__ partAll,
                                               float* __restrict__ partOut,
                                               int* __restrict__ ctrs,
                                               float* __restrict__ out) {
    int rt  = blockIdx.x;
    int tid = threadIdx.x;
    int l = tid >> 2, i = tid & 3;
    int r   = (l >> 4) * 4 + i;        // row within tile (fixed per thread)
    int col = l & 15;

    int np       = cntW[labels[rt]];
    int off      = tileOff[rt];
    int selfRank = posRank[rt];

    __shared__ float tile[MAXNP * 256];
    __shared__ float shA[16][17];
    __shared__ float shB[16][17];
    __shared__ float nsSh[16], PSh[16];
    __shared__ int winS;
    __shared__ float red[256];

    float sE = 0.f, sP = 0.f;
    const float* src = posBuf + (size_t)off * 256 + tid;
    for (int j = 0; j < np; ++j) {
        float c = src[j * 256];
        tile[j * 256 + tid] = c;
        float l2 = __builtin_fmaf(c, K1, -K1);
        sE += exp2f(l2);
        bool diag = (j == selfRank) & (col == r);
        sP += diag ? 0.f : l2;
    }
    shA[r][col] = sE;
    shB[r][col] = sP;
    __syncthreads();
    if (tid < 16) {
        float e = 0.f, p = 0.f;
#pragma unroll
        for (int cc = 0; cc < 16; ++cc) { e += shA[tid][cc]; p += shB[tid][cc]; }
        const float* pa = partAll + (size_t)(rt * 16 + tid) * NPART;
        float sall = 0.f;
#pragma unroll
        for (int q = 0; q < 16; ++q) {
            float4 v = *(const float4*)(pa + q * 4);
            sall += v.x + v.y + v.z + v.w;
        }
        nsSh[tid] = sall - e;          // negative-pair exp sum
        PSh[tid]  = p;
    }
    __syncthreads();

    float nsv = nsSh[r];
    float sL = 0.f;
    for (int j = 0; j < np; ++j) {
        float c  = tile[j * 256 + tid];
        float l2 = __builtin_fmaf(c, K1, -K1);
        float lg = __log2f(exp2f(l2) + nsv);
        bool diag = (j == selfRank) & (col == r);
        sL += diag ? 0.f : lg;
    }
    __syncthreads();
    shA[r][col] = sL;
    __syncthreads();
    if (tid < 16) {
        float L = 0.f;
#pragma unroll
        for (int cc = 0; cc < 16; ++cc) L += shA[tid][cc];
        float npRow = (float)(16 * np - 1);
        shB[0][tid] = (PSh[tid] - L) / npRow;
    }
    __syncthreads();
    if (tid == 0) {
        float sx = 0.f;
#pragma unroll
        for (int q = 0; q < 16; ++q) sx += shB[0][q];
        partOut[rt] = sx;
    }

    // ---- fused final: last of the 256 blocks reduces partOut -> out ----
    __syncthreads();
    if (tid == 0) {
        __threadfence();               // release partOut[rt]
        winS = (atomicAdd(&ctrs[0], 1) == N_ANCH - 1);
    }
    __syncthreads();
    if (!winS) return;
    __threadfence();                   // acquire all partOut

    red[tid] = partOut[tid];
    __syncthreads();
    for (int o2 = 128; o2; o2 >>= 1) {
        if (tid < o2) red[tid] += red[tid + o2];
        __syncthreads();
    }
    if (tid == 0) out[0] = -red[0] * (LN2 / (float)N_TOT);
}

extern "C" void kernel_launch(void* const* d_in, const int* in_sizes, int n_in,
                              void* d_out, int out_size, void* d_ws, size_t ws_size,
                              hipStream_t stream) {
    const float* feats  = (const float*)d_in[0];
    const int*   labels = (const int*)d_in[1];
    float* out = (float*)d_out;

    char* ws = (char*)d_ws;
    ushort* xb      = (ushort*)ws;                                  // 2 MB
    float*  partAll = (float*)(ws + (2u << 20));                    // 1 MB (4096*64 f32)
    float*  posBuf  = (float*)(ws + (3u << 20));                    // 8 MB
    char*   meta    = ws + (11u << 20);
    int*    cntW    = (int*)meta;                                   // 32 ints
    int*    posRank = (int*)(meta + 128);                           // 256 ints
    int*    tileOff = (int*)(meta + 128 + 1024);                    // 256 ints
    float*  partOut = (float*)(meta + 128 + 2048);                  // 256 floats
    int*    ctrs    = (int*)(meta + 128 + 2048 + 1024);             // 4 ints

    k_prep <<<512, 256, 0, stream>>>(feats, labels, xb, cntW, posRank, tileOff, ctrs);
    k_pass1<<<1024, 256, 0, stream>>>(xb, labels, posRank, tileOff, partAll, posBuf);
    k_passB<<<N_ANCH, 256, 0, stream>>>(posBuf, labels, cntW, posRank, tileOff,
                                        partAll, partOut, ctrs, out);
}

// Round 10
// 37.444 us; speedup vs baseline: 3.2247x; 1.0800x over previous
//
#include <hip/hip_runtime.h>
#include <hip/hip_bf16.h>

#define D_DIM   256
#define N_TOT   4096
#define N_ANCH  256
#define NGRP    32                    // anchor groups of 8 (128 rows)
#define NBLK    528                   // NGRP*(NGRP+1)/2 upper-triangle blocks
#define NPART   64                    // partAll slots per row
#define K1  20.60992915555662f        // (1/0.07) * log2(e)
#define LN2 0.6931471805599453f
#define MAXNP    48                   // max anchors per label (19 labels, mean 13.5)

typedef __attribute__((ext_vector_type(8))) short bf16x8;
typedef __attribute__((ext_vector_type(4))) float f32x4;

#define MFMA(a, b, c) __builtin_amdgcn_mfma_f32_16x16x32_bf16((a), (b), (c), 0, 0, 0)

__device__ __forceinline__ ushort f2bf(float f) {
    union { float f; unsigned u; } a; a.f = f;
    unsigned u = a.u;
    u = (u + 0x7FFFu + ((u >> 16) & 1u)) >> 16;   // RNE
    return (ushort)u;
}

// ---------- kernel 0: fp32 -> bf16 convert; block 0 also does label setup ----------
__global__ void __launch_bounds__(256) k_convert(const float* __restrict__ feats,
                                                 const int* __restrict__ labels,
                                                 ushort* __restrict__ xb,
                                                 int* __restrict__ cntW,
                                                 int* __restrict__ posRank,
                                                 int* __restrict__ tileOff) {
    int idx = blockIdx.x * 256 + threadIdx.x;
    int base = idx * 4;
    float4 v = *(const float4*)(feats + base);
    ushort4 o;
    o.x = f2bf(v.x); o.y = f2bf(v.y); o.z = f2bf(v.z); o.w = f2bf(v.w);
    *(ushort4*)(xb + base) = o;

    if (blockIdx.x == 0) {
        __shared__ int labS[N_ANCH];
        __shared__ int cntS[32];
        int t = threadIdx.x;
        if (t < 32) cntS[t] = 0;
        labS[t] = labels[t];
        __syncthreads();
        atomicAdd(&cntS[labS[t]], 1);
        __syncthreads();
        int myLab = labS[t];
        int rank = 0, toff = 0;
        for (int b = 0; b < t; ++b) {
            int lb = labS[b];
            rank += (lb == myLab);
            toff += cntS[lb];
        }
        posRank[t] = rank;
        tileOff[t] = toff;
        if (t < 32) cntW[t] = cntS[t];
    }
}

// ---------- kernel 1: symmetric 128x128-tile fused GEMM sweep (upper triangle) ----------
// 528 blocks (g<=s), 256 threads = 4 waves (2x2). Each wave: 64x64 output.
// K=256 in two BK=128 chunks through one 64 KB swizzled LDS buffer.
// Off-diag tiles contribute row sums to group g AND col sums (transpose) to group s.
__global__ void __launch_bounds__(256, 2) k_pass1(const ushort* __restrict__ xb,
                                                  const int* __restrict__ labels,
                                                  const int* __restrict__ posRank,
                                                  const int* __restrict__ tileOff,
                                                  float* __restrict__ partAll,
                                                  float* __restrict__ posBuf) {
    __shared__ __align__(16) char lds[65536];   // A: [0,32K), B: [32K,64K)

    // triangular decode (block-uniform scalar loop, <=32 iters)
    int rem = blockIdx.x, g = 0;
    while (rem >= NGRP - g) { rem -= NGRP - g; ++g; }
    const int s = g + rem;                      // g <= s

    const int tid = threadIdx.x;
    const int lane = tid & 63, wid = tid >> 6;
    const int lrow = lane & 15, khalf = lane >> 4;
    const int wr = wid >> 1, wc = wid & 1;      // wave sub-tile (wr*64, wc*64)

    const char* aSrc = (const char*)(xb + (size_t)g * 128 * D_DIM);
    const char* bSrc = (const char*)(xb + (size_t)s * 128 * D_DIM);

    // staging address decode (8 x 16B per thread per operand per chunk)
    uint32_t Lg[8], Lw[8];
#pragma unroll
    for (int o = 0; o < 8; ++o) {
        uint32_t L = (uint32_t)(tid * 16 + o * 4096);      // linear LDS byte
        Lg[o] = (L >> 8) * 512 + (L & 255);                // global byte in chunk
        Lw[o] = L ^ (((L >> 8) & 7u) << 4);                // swizzled LDS byte
    }

    bf16x8 stA[8], stB[8];
    auto loadch = [&](int kc) {
#pragma unroll
        for (int o = 0; o < 8; ++o) {
            stA[o] = *(const bf16x8*)(aSrc + Lg[o] + kc * 256);
            stB[o] = *(const bf16x8*)(bSrc + Lg[o] + kc * 256);
        }
    };
    auto writelds = [&]() {
#pragma unroll
        for (int o = 0; o < 8; ++o) {
            *(bf16x8*)(lds + Lw[o])         = stA[o];
            *(bf16x8*)(lds + 32768 + Lw[o]) = stB[o];
        }
    };

    f32x4 acc[4][4];
#pragma unroll
    for (int m = 0; m < 4; ++m)
#pragma unroll
        for (int n = 0; n < 4; ++n)
            acc[m][n] = (f32x4){0.f, 0.f, 0.f, 0.f};

    const uint32_t swz = (uint32_t)((lrow & 7) << 4);
    auto compute = [&]() {
#pragma unroll
        for (int ks = 0; ks < 4; ++ks) {
            bf16x8 af[4], bfr[4];
#pragma unroll
            for (int m = 0; m < 4; ++m) {
                uint32_t row = (uint32_t)(wr * 64 + m * 16 + lrow);
                af[m] = *(const bf16x8*)(lds + ((row * 256 + ks * 64 + khalf * 16) ^ swz));
            }
#pragma unroll
            for (int n = 0; n < 4; ++n) {
                uint32_t row = (uint32_t)(wc * 64 + n * 16 + lrow);
                bfr[n] = *(const bf16x8*)(lds + 32768 + ((row * 256 + ks * 64 + khalf * 16) ^ swz));
            }
#pragma unroll
            for (int m = 0; m < 4; ++m)
#pragma unroll
                for (int n = 0; n < 4; ++n)
                    acc[m][n] = MFMA(af[m], bfr[n], acc[m][n]);
        }
    };

    loadch(0);
    writelds();
    __syncthreads();        // chunk 0 ready
    loadch(1);              // prefetch chunk 1 (hides under compute)
    compute();
    __syncthreads();        // all reads of chunk 0 done
    writelds();
    __syncthreads();        // chunk 1 ready
    compute();
    __syncthreads();        // all LDS reads done -> LDS reusable as scratch

    // ---- epilogue: row sums (direct) + col sums (transpose) + positive stores ----
    const int raBase = g * 8 + wr * 4, caBase = s * 8 + wc * 4;
    int labR[4], offR[4], rankR[4], labC[4], rankC[4], offC[4];
#pragma unroll
    for (int m = 0; m < 4; ++m) {
        labR[m]  = labels[raBase + m];
        offR[m]  = tileOff[raBase + m];
        rankR[m] = posRank[raBase + m];
    }
#pragma unroll
    for (int n = 0; n < 4; ++n) {
        labC[n]  = labels[caBase + n];
        rankC[n] = posRank[caBase + n];
        offC[n]  = tileOff[caBase + n];
    }

    float aAll[4][4];       // direct row sums [m][i]
    float colP[4];          // per-lane col partials [n] (col = lrow)
#pragma unroll
    for (int m = 0; m < 4; ++m)
#pragma unroll
        for (int i = 0; i < 4; ++i) aAll[m][i] = 0.f;
#pragma unroll
    for (int n = 0; n < 4; ++n) colP[n] = 0.f;

    float* scr = (float*)lds + wid * 256;   // 1 KB per-wave transpose scratch

#pragma unroll
    for (int m = 0; m < 4; ++m) {
#pragma unroll
        for (int n = 0; n < 4; ++n) {
            f32x4 c = acc[m][n];
            float e[4];
#pragma unroll
            for (int i = 0; i < 4; ++i) {
                e[i] = exp2f(__builtin_fmaf(c[i], K1, -K1));
                aAll[m][i] += e[i];
            }
            if (g != s)
                colP[n] += e[0] + e[1] + e[2] + e[3];
            if (labR[m] == labC[n]) {    // wave-uniform positive tile
                // direct store: tile (row-anchor raBase+m, col-anchor caBase+n)
                *(f32x4*)(posBuf + (size_t)(offR[m] + rankC[n]) * 256 + lane * 4) = c;
                if (g != s) {
                    // transpose store via LDS bounce: tile (caBase+n, raBase+m)
#pragma unroll
                    for (int i = 0; i < 4; ++i)
                        scr[(khalf * 4 + i) * 16 + lrow] = c[i];
                    __builtin_amdgcn_s_waitcnt(0);          // lgkmcnt(0): wave-local LDS RAW
                    f32x4 tr = *(f32x4*)(scr + lrow * 16 + khalf * 4);
                    *(f32x4*)(posBuf + (size_t)(offC[n] + rankR[m]) * 256 + lane * 4) = tr;
                }
            }
        }
    }

    // direct row-sum reduce over the 16-lane col groups
#pragma unroll
    for (int msk = 1; msk < 16; msk <<= 1)
#pragma unroll
        for (int m = 0; m < 4; ++m)
#pragma unroll
            for (int i = 0; i < 4; ++i)
                aAll[m][i] += __shfl_xor(aAll[m][i], msk, 64);

    if (lrow == 0) {
#pragma unroll
        for (int m = 0; m < 4; ++m)
#pragma unroll
            for (int i = 0; i < 4; ++i) {
                int row = g * 128 + wr * 64 + m * 16 + khalf * 4 + i;
                partAll[row * NPART + s * 2 + wc] = aAll[m][i];
            }
    }

    // transpose col-sum reduce over the 4 khalf groups; write to group s rows
    if (g != s) {
#pragma unroll
        for (int msk = 16; msk < 64; msk <<= 1)
#pragma unroll
            for (int n = 0; n < 4; ++n)
                colP[n] += __shfl_xor(colP[n], msk, 64);
        if (lane < 16) {
#pragma unroll
            for (int n = 0; n < 4; ++n) {
                int row = s * 128 + wc * 64 + n * 16 + lane;
                partAll[row * NPART + g * 2 + wr] = colP[n];
            }
        }
    }
}

// ---------- kernel 2: elementwise positive pass ----------
__global__ void __launch_bounds__(256) k_passB(const float* __restrict__ posBuf,
                                               const int* __restrict__ labels,
                                               const int* __restrict__ cntW,
                                               const int* __restrict__ posRank,
                                               const int* __restrict__ tileOff,
                                               const float* __restrict__ partAll,
                                               float* __restrict__ partOut) {
    int rt  = blockIdx.x;
    int tid = threadIdx.x;
    int l = tid >> 2, i = tid & 3;
    int r   = (l >> 4) * 4 + i;        // row within tile (fixed per thread)
    int col = l & 15;

    int np       = cntW[labels[rt]];
    int off      = tileOff[rt];
    int selfRank = posRank[rt];

    __shared__ float tile[MAXNP * 256];
    __shared__ float shA[16][17];
    __shared__ float shB[16][17];
    __shared__ float nsSh[16], PSh[16];

    float sE = 0.f, sP = 0.f;
    const float* src = posBuf + (size_t)off * 256 + tid;
    for (int j = 0; j < np; ++j) {
        float c = src[j * 256];
        tile[j * 256 + tid] = c;
        float l2 = __builtin_fmaf(c, K1, -K1);
        sE += exp2f(l2);
        bool diag = (j == selfRank) & (col == r);
        sP += diag ? 0.f : l2;
    }
    shA[r][col] = sE;
    shB[r][col] = sP;
    __syncthreads();
    if (tid < 16) {
        float e = 0.f, p = 0.f;
#pragma unroll
        for (int cc = 0; cc < 16; ++cc) { e += shA[tid][cc]; p += shB[tid][cc]; }
        const float* pa = partAll + (size_t)(rt * 16 + tid) * NPART;
        float sall = 0.f;
#pragma unroll
        for (int q = 0; q < 16; ++q) {
            float4 v = *(const float4*)(pa + q * 4);
            sall += v.x + v.y + v.z + v.w;
        }
        nsSh[tid] = sall - e;          // negative-pair exp sum
        PSh[tid]  = p;
    }
    __syncthreads();

    float nsv = nsSh[r];
    float sL = 0.f;
    for (int j = 0; j < np; ++j) {
        float c  = tile[j * 256 + tid];
        float l2 = __builtin_fmaf(c, K1, -K1);
        float lg = __log2f(exp2f(l2) + nsv);
        bool diag = (j == selfRank) & (col == r);
        sL += diag ? 0.f : lg;
    }
    __syncthreads();
    shA[r][col] = sL;
    __syncthreads();
    if (tid < 16) {
        float L = 0.f;
#pragma unroll
        for (int cc = 0; cc < 16; ++cc) L += shA[tid][cc];
        float npRow = (float)(16 * np - 1);
        shB[0][tid] = (PSh[tid] - L) / npRow;
    }
    __syncthreads();
    if (tid == 0) {
        float sx = 0.f;
#pragma unroll
        for (int q = 0; q < 16; ++q) sx += shB[0][q];
        partOut[rt] = sx;
    }
}

// ---------- kernel 3: final reduction ----------
__global__ void __launch_bounds__(256) k_final(const float* __restrict__ partOut,
                                               float* __restrict__ out) {
    __shared__ float red[256];
    int t = threadIdx.x;
    red[t] = partOut[t];
    __syncthreads();
    for (int o = 128; o; o >>= 1) {
        if (t < o) red[t] += red[t + o];
        __syncthreads();
    }
    if (t == 0) out[0] = -red[0] * (LN2 / (float)N_TOT);
}

extern "C" void kernel_launch(void* const* d_in, const int* in_sizes, int n_in,
                              void* d_out, int out_size, void* d_ws, size_t ws_size,
                              hipStream_t stream) {
    const float* feats  = (const float*)d_in[0];
    const int*   labels = (const int*)d_in[1];
    float* out = (float*)d_out;

    char* ws = (char*)d_ws;
    ushort* xb      = (ushort*)ws;                                  // 2 MB
    float*  partAll = (float*)(ws + (2u << 20));                    // 1 MB (4096*64 f32)
    float*  posBuf  = (float*)(ws + (3u << 20));                    // 8 MB
    char*   meta    = ws + (11u << 20);
    int*    cntW    = (int*)meta;                                   // 32 ints
    int*    posRank = (int*)(meta + 128);                           // 256 ints
    int*    tileOff = (int*)(meta + 128 + 1024);                    // 256 ints
    float*  partOut = (float*)(meta + 128 + 2048);                  // 256 floats

    k_convert<<<1024, 256, 0, stream>>>(feats, labels, xb, cntW, posRank, tileOff);
    k_pass1  <<<NBLK, 256, 0, stream>>>(xb, labels, posRank, tileOff, partAll, posBuf);
    k_passB  <<<N_ANCH, 256, 0, stream>>>(posBuf, labels, cntW, posRank, tileOff,
                                          partAll, partOut);
    k_final  <<<1, 256, 0, stream>>>(partOut, out);
}

// Round 11
// 32.553 us; speedup vs baseline: 3.7092x; 1.1503x over previous
//
#include <hip/hip_runtime.h>
#include <hip/hip_bf16.h>

#define D_DIM   256
#define N_TOT   4096
#define N_ANCH  256
#define NGRP    32                    // anchor groups of 8 (128 rows)
#define NBLK    528                   // NGRP*(NGRP+1)/2 upper-triangle blocks
#define NPART   64                    // partAll slots per row
#define K1  20.60992915555662f        // (1/0.07) * log2(e)
#define LN2 0.6931471805599453f
#define MAXNP    48                   // max anchors per label (19 labels, mean 13.5)

typedef __attribute__((ext_vector_type(8))) short bf16x8;
typedef __attribute__((ext_vector_type(4))) float f32x4;

#define MFMA(a, b, c) __builtin_amdgcn_mfma_f32_16x16x32_bf16((a), (b), (c), 0, 0, 0)

__device__ __forceinline__ bf16x8 cvt8(const float4 a, const float4 b) {
    union { uint32_t w[4]; bf16x8 v; } u;
    asm("v_cvt_pk_bf16_f32 %0, %1, %2" : "=v"(u.w[0]) : "v"(a.x), "v"(a.y));
    asm("v_cvt_pk_bf16_f32 %0, %1, %2" : "=v"(u.w[1]) : "v"(a.z), "v"(a.w));
    asm("v_cvt_pk_bf16_f32 %0, %1, %2" : "=v"(u.w[2]) : "v"(b.x), "v"(b.y));
    asm("v_cvt_pk_bf16_f32 %0, %1, %2" : "=v"(u.w[3]) : "v"(b.z), "v"(b.w));
    return u.v;
}

// ---------- kernel 1: symmetric 128x128-tile fused GEMM (fp32 in, inline bf16 cvt) ----------
// 528 blocks (g<=s, XCD-swizzled), 256 threads = 4 waves (2x2). Each wave: 64x64 out.
// K=256 in two BK=128 chunks through one 64 KB swizzled LDS buffer; staging loads
// fp32 from feats and converts in-register (v_cvt_pk_bf16_f32).
// Per-block metadata (posRank/tileOff for its 16 anchors) computed in-block.
__global__ void __launch_bounds__(256, 2) k_pass1(const float* __restrict__ feats,
                                                  const int* __restrict__ labels,
                                                  float* __restrict__ partAll,
                                                  float* __restrict__ posBuf,
                                                  float* __restrict__ out) {
    __shared__ __align__(16) char lds[65536];   // A: [0,32K), B: [32K,64K)
    __shared__ int labS[N_ANCH];
    __shared__ int cntS[32];
    __shared__ int metaRank[16], metaToff[16];

    if (blockIdx.x == 0 && threadIdx.x == 0) out[0] = 0.f;   // passB accumulates later

    // XCD swizzle (bijective: 528 = 8*66), then triangular decode g<=s
    int swzId = (blockIdx.x & 7) * 66 + (blockIdx.x >> 3);
    int rem = swzId, g = 0;
    while (rem >= NGRP - g) { rem -= NGRP - g; ++g; }
    const int s = g + rem;

    const int tid = threadIdx.x;
    const int lane = tid & 63, wid = tid >> 6;
    const int lrow = lane & 15, khalf = lane >> 4;
    const int wr = wid >> 1, wc = wid & 1;      // wave sub-tile (wr*64, wc*64)

    // label table + histogram (shared across staging)
    labS[tid] = labels[tid];
    if (tid < 32) cntS[tid] = 0;
    __syncthreads();
    atomicAdd(&cntS[labS[tid]], 1);

    const char* aSrcF = (const char*)(feats + (size_t)g * 128 * D_DIM);
    const char* bSrcF = (const char*)(feats + (size_t)s * 128 * D_DIM);

    // staging decode: linear LDS byte L -> fp32 source offset + swizzled LDS byte
    uint32_t LgF[8], Lw[8];
#pragma unroll
    for (int o = 0; o < 8; ++o) {
        uint32_t L = (uint32_t)(tid * 16 + o * 4096);      // linear chunk byte (bf16)
        LgF[o] = (L >> 8) * 1024 + ((L & 255) << 1);       // row*1024B + colelem*4B
        Lw[o]  = L ^ (((L >> 8) & 7u) << 4);               // swizzled LDS byte
    }

    auto stage = [&](int kc) {
        float4 fa[8][2], fb[8][2];
#pragma unroll
        for (int o = 0; o < 8; ++o) {
            const char* pa = aSrcF + LgF[o] + kc * 512;
            const char* pb = bSrcF + LgF[o] + kc * 512;
            fa[o][0] = *(const float4*)pa;  fa[o][1] = *(const float4*)(pa + 16);
            fb[o][0] = *(const float4*)pb;  fb[o][1] = *(const float4*)(pb + 16);
        }
#pragma unroll
        for (int o = 0; o < 8; ++o) {
            *(bf16x8*)(lds + Lw[o])         = cvt8(fa[o][0], fa[o][1]);
            *(bf16x8*)(lds + 32768 + Lw[o]) = cvt8(fb[o][0], fb[o][1]);
        }
    };

    f32x4 acc[4][4];
#pragma unroll
    for (int m = 0; m < 4; ++m)
#pragma unroll
        for (int n = 0; n < 4; ++n)
            acc[m][n] = (f32x4){0.f, 0.f, 0.f, 0.f};

    const uint32_t swz = (uint32_t)((lrow & 7) << 4);
    auto compute = [&]() {
#pragma unroll
        for (int ks = 0; ks < 4; ++ks) {
            bf16x8 af[4], bfr[4];
#pragma unroll
            for (int m = 0; m < 4; ++m) {
                uint32_t row = (uint32_t)(wr * 64 + m * 16 + lrow);
                af[m] = *(const bf16x8*)(lds + ((row * 256 + ks * 64 + khalf * 16) ^ swz));
            }
#pragma unroll
            for (int n = 0; n < 4; ++n) {
                uint32_t row = (uint32_t)(wc * 64 + n * 16 + lrow);
                bfr[n] = *(const bf16x8*)(lds + 32768 + ((row * 256 + ks * 64 + khalf * 16) ^ swz));
            }
#pragma unroll
            for (int m = 0; m < 4; ++m)
#pragma unroll
                for (int n = 0; n < 4; ++n)
                    acc[m][n] = MFMA(af[m], bfr[n], acc[m][n]);
        }
    };

    stage(0);
    __syncthreads();        // chunk 0 ready; histogram done

    // per-block metadata: 16 anchors x 16 workers (rank = #same-label before,
    // toff = sum of label counts before), reduced over the 16-lane groups
    {
        int aIdx = tid >> 4, q = tid & 15;
        int aAnchor = (aIdx < 8) ? (g * 8 + aIdx) : (s * 8 + aIdx - 8);
        int la = labS[aAnchor];
        int rk = 0, tf = 0;
        for (int b = q; b < aAnchor; b += 16) {
            int lb = labS[b];
            rk += (lb == la);
            tf += cntS[lb];
        }
#pragma unroll
        for (int msk = 1; msk < 16; msk <<= 1) {
            rk += __shfl_xor(rk, msk, 64);
            tf += __shfl_xor(tf, msk, 64);
        }
        if (q == 0) { metaRank[aIdx] = rk; metaToff[aIdx] = tf; }
    }

    compute();              // chunk 0
    __syncthreads();        // all reads of chunk 0 done
    stage(1);
    __syncthreads();        // chunk 1 ready (and metaRank/Toff visible)
    compute();
    __syncthreads();        // all LDS reads done -> LDS reusable as scratch

    // ---- epilogue: row sums (direct) + col sums (transpose) + positive stores ----
    const int raBase = g * 8 + wr * 4, caBase = s * 8 + wc * 4;
    int labR[4], offR[4], rankR[4], labC[4], rankC[4], offC[4];
#pragma unroll
    for (int m = 0; m < 4; ++m) {
        labR[m]  = labS[raBase + m];
        offR[m]  = metaToff[wr * 4 + m];
        rankR[m] = metaRank[wr * 4 + m];
    }
#pragma unroll
    for (int n = 0; n < 4; ++n) {
        labC[n]  = labS[caBase + n];
        rankC[n] = metaRank[8 + wc * 4 + n];
        offC[n]  = metaToff[8 + wc * 4 + n];
    }

    float aAll[4][4];       // direct row sums [m][i]
    float colP[4];          // per-lane col partials [n] (col = lrow)
#pragma unroll
    for (int m = 0; m < 4; ++m)
#pragma unroll
        for (int i = 0; i < 4; ++i) aAll[m][i] = 0.f;
#pragma unroll
    for (int n = 0; n < 4; ++n) colP[n] = 0.f;

    float* scr = (float*)lds + wid * 256;   // 1 KB per-wave transpose scratch

#pragma unroll
    for (int m = 0; m < 4; ++m) {
#pragma unroll
        for (int n = 0; n < 4; ++n) {
            f32x4 c = acc[m][n];
            float e[4];
#pragma unroll
            for (int i = 0; i < 4; ++i) {
                e[i] = exp2f(__builtin_fmaf(c[i], K1, -K1));
                aAll[m][i] += e[i];
            }
            if (g != s)
                colP[n] += e[0] + e[1] + e[2] + e[3];
            if (labR[m] == labC[n]) {    // wave-uniform positive tile
                *(f32x4*)(posBuf + (size_t)(offR[m] + rankC[n]) * 256 + lane * 4) = c;
                if (g != s) {
                    // transpose store via LDS bounce: tile (caBase+n, raBase+m)
#pragma unroll
                    for (int i = 0; i < 4; ++i)
                        scr[(khalf * 4 + i) * 16 + lrow] = c[i];
                    __builtin_amdgcn_s_waitcnt(0);          // wave-local LDS RAW
                    f32x4 tr = *(f32x4*)(scr + lrow * 16 + khalf * 4);
                    *(f32x4*)(posBuf + (size_t)(offC[n] + rankR[m]) * 256 + lane * 4) = tr;
                }
            }
        }
    }

    // direct row-sum reduce over the 16-lane col groups
#pragma unroll
    for (int msk = 1; msk < 16; msk <<= 1)
#pragma unroll
        for (int m = 0; m < 4; ++m)
#pragma unroll
            for (int i = 0; i < 4; ++i)
                aAll[m][i] += __shfl_xor(aAll[m][i], msk, 64);

    if (lrow == 0) {
#pragma unroll
        for (int m = 0; m < 4; ++m)
#pragma unroll
            for (int i = 0; i < 4; ++i) {
                int row = g * 128 + wr * 64 + m * 16 + khalf * 4 + i;
                partAll[row * NPART + s * 2 + wc] = aAll[m][i];
            }
    }

    // transpose col-sum reduce over the 4 khalf groups; write to group s rows
    if (g != s) {
#pragma unroll
        for (int msk = 16; msk < 64; msk <<= 1)
#pragma unroll
            for (int n = 0; n < 4; ++n)
                colP[n] += __shfl_xor(colP[n], msk, 64);
        if (lane < 16) {
#pragma unroll
            for (int n = 0; n < 4; ++n) {
                int row = s * 128 + wc * 64 + n * 16 + lane;
                partAll[row * NPART + g * 2 + wr] = colP[n];
            }
        }
    }
}

// ---------- kernel 2: elementwise positive pass + atomic final ----------
__global__ void __launch_bounds__(256) k_passB(const float* __restrict__ posBuf,
                                               const int* __restrict__ labels,
                                               const float* __restrict__ partAll,
                                               float* __restrict__ out) {
    int rt  = blockIdx.x;
    int tid = threadIdx.x;
    int l = tid >> 2, i = tid & 3;
    int r   = (l >> 4) * 4 + i;        // row within tile (fixed per thread)
    int col = l & 15;

    __shared__ float tile[MAXNP * 256];
    __shared__ float shA[16][17];
    __shared__ float shB[16][17];
    __shared__ float nsSh[16], PSh[16];
    __shared__ int labS[N_ANCH];
    __shared__ int cntS[32];
    __shared__ int wRk[4], wTf[4];
    __shared__ int mNp, mOff, mRank;

    // in-block metadata for anchor rt
    labS[tid] = labels[tid];
    if (tid < 32) cntS[tid] = 0;
    __syncthreads();
    atomicAdd(&cntS[labS[tid]], 1);
    __syncthreads();
    {
        int la = labS[rt];
        int rk = 0, tf = 0;
        if (tid < rt) { int lb = labS[tid]; rk = (lb == la) ? 1 : 0; tf = cntS[lb]; }
#pragma unroll
        for (int msk = 1; msk < 64; msk <<= 1) {
            rk += __shfl_xor(rk, msk, 64);
            tf += __shfl_xor(tf, msk, 64);
        }
        if ((tid & 63) == 0) { wRk[tid >> 6] = rk; wTf[tid >> 6] = tf; }
        __syncthreads();
        if (tid == 0) {
            mNp   = cntS[la];
            mRank = wRk[0] + wRk[1] + wRk[2] + wRk[3];
            mOff  = wTf[0] + wTf[1] + wTf[2] + wTf[3];
        }
        __syncthreads();
    }
    int np = mNp, off = mOff, selfRank = mRank;

    float sE = 0.f, sP = 0.f;
    const float* src = posBuf + (size_t)off * 256 + tid;
    for (int j = 0; j < np; ++j) {
        float c = src[j * 256];
        tile[j * 256 + tid] = c;
        float l2 = __builtin_fmaf(c, K1, -K1);
        sE += exp2f(l2);
        bool diag = (j == selfRank) & (col == r);
        sP += diag ? 0.f : l2;
    }
    shA[r][col] = sE;
    shB[r][col] = sP;
    __syncthreads();
    if (tid < 16) {
        float e = 0.f, p = 0.f;
#pragma unroll
        for (int cc = 0; cc < 16; ++cc) { e += shA[tid][cc]; p += shB[tid][cc]; }
        const float* pa = partAll + (size_t)(rt * 16 + tid) * NPART;
        float sall = 0.f;
#pragma unroll
        for (int q = 0; q < 16; ++q) {
            float4 v = *(const float4*)(pa + q * 4);
            sall += v.x + v.y + v.z + v.w;
        }
        nsSh[tid] = sall - e;          // negative-pair exp sum
        PSh[tid]  = p;
    }
    __syncthreads();

    float nsv = nsSh[r];
    float sL = 0.f;
    for (int j = 0; j < np; ++j) {
        float c  = tile[j * 256 + tid];
        float l2 = __builtin_fmaf(c, K1, -K1);
        float lg = __log2f(exp2f(l2) + nsv);
        bool diag = (j == selfRank) & (col == r);
        sL += diag ? 0.f : lg;
    }
    __syncthreads();
    shA[r][col] = sL;
    __syncthreads();
    if (tid < 16) {
        float L = 0.f;
#pragma unroll
        for (int cc = 0; cc < 16; ++cc) L += shA[tid][cc];
        float npRow = (float)(16 * np - 1);
        shB[0][tid] = (PSh[tid] - L) / npRow;
    }
    __syncthreads();
    if (tid == 0) {
        float sx = 0.f;
#pragma unroll
        for (int q = 0; q < 16; ++q) sx += shB[0][q];
        atomicAdd(out, -sx * (LN2 / (float)N_TOT));   // out zeroed by pass1 block 0
    }
}

extern "C" void kernel_launch(void* const* d_in, const int* in_sizes, int n_in,
                              void* d_out, int out_size, void* d_ws, size_t ws_size,
                              hipStream_t stream) {
    const float* feats  = (const float*)d_in[0];
    const int*   labels = (const int*)d_in[1];
    float* out = (float*)d_out;

    char* ws = (char*)d_ws;
    float*  partAll = (float*)(ws + (2u << 20));                    // 1 MB (4096*64 f32)
    float*  posBuf  = (float*)(ws + (3u << 20));                    // 8 MB

    k_pass1<<<NBLK, 256, 0, stream>>>(feats, labels, partAll, posBuf, out);
    k_passB<<<N_ANCH, 256, 0, stream>>>(posBuf, labels, partAll, out);
}

// Round 13
// 30.871 us; speedup vs baseline: 3.9112x; 1.0545x over previous
//
#include <hip/hip_runtime.h>
#include <hip/hip_bf16.h>

#define D_DIM   256
#define N_TOT   4096
#define N_ANCH  256
#define NGRP    32                    // anchor groups of 8 (128 rows)
#define NOFF    496                   // strict upper-triangle tiles (g<s)
#define NBLK    512                   // 496 off-diag + 16 dual-diagonal blocks
#define NPART   64                    // partAll slots per row
#define K1  20.60992915555662f        // (1/0.07) * log2(e)
#define LN2 0.6931471805599453f
#define MAXNP    48                   // max anchors per label (19 labels, mean 13.5)

typedef __attribute__((ext_vector_type(8))) short bf16x8;
typedef __attribute__((ext_vector_type(4))) float f32x4;

#define MFMA(a, b, c) __builtin_amdgcn_mfma_f32_16x16x32_bf16((a), (b), (c), 0, 0, 0)

__device__ __forceinline__ bf16x8 cvt8(const float4 a, const float4 b) {
    union { uint32_t w[4]; bf16x8 v; } u;
    asm("v_cvt_pk_bf16_f32 %0, %1, %2" : "=v"(u.w[0]) : "v"(a.x), "v"(a.y));
    asm("v_cvt_pk_bf16_f32 %0, %1, %2" : "=v"(u.w[1]) : "v"(a.z), "v"(a.w));
    asm("v_cvt_pk_bf16_f32 %0, %1, %2" : "=v"(u.w[2]) : "v"(b.x), "v"(b.y));
    asm("v_cvt_pk_bf16_f32 %0, %1, %2" : "=v"(u.w[3]) : "v"(b.z), "v"(b.w));
    return u.v;
}

// ---------- kernel 1: symmetric 128x128-tile fused GEMM (fp32 in, inline bf16 cvt) ----------
// 512 blocks: 0..495 strict-upper tiles (XCD-swizzled), 496..511 two diagonal tiles each.
// 256 threads = 4 waves (2x2); each wave 64x64 out. K=256 in two BK=128 chunks through
// one 64 KB swizzled LDS buffer. A chunk-1 is register-prefetched during compute(0).
__global__ void __launch_bounds__(256, 2) k_pass1(const float* __restrict__ feats,
                                                  const int* __restrict__ labels,
                                                  float* __restrict__ partAll,
                                                  float* __restrict__ posBuf,
                                                  float* __restrict__ out) {
    __shared__ __align__(16) char lds[65536];   // A: [0,32K), B: [32K,64K)
    __shared__ int labS[N_ANCH];
    __shared__ int cntS[32];
    __shared__ int metaRank[16], metaToff[16];

    if (blockIdx.x == 0 && threadIdx.x == 0) out[0] = 0.f;   // passB accumulates later

    const int tid = threadIdx.x;
    const int lane = tid & 63, wid = tid >> 6;
    const int lrow = lane & 15, khalf = lane >> 4;
    const int wr = wid >> 1, wc = wid & 1;      // wave sub-tile (wr*64, wc*64)

    // label table + histogram (persists across tiles)
    labS[tid] = labels[tid];
    if (tid < 32) cntS[tid] = 0;
    __syncthreads();
    atomicAdd(&cntS[labS[tid]], 1);
    // (first in-tile __syncthreads covers the histogram)

    // staging decode: linear bf16 LDS byte L -> fp32 source offset + swizzled LDS byte
    uint32_t LgF[8], Lw[8];
#pragma unroll
    for (int o = 0; o < 8; ++o) {
        uint32_t L = (uint32_t)(tid * 16 + o * 4096);
        LgF[o] = (L >> 8) * 1024 + ((L & 255) << 1);       // row*1024B + colelem*4B
        Lw[o]  = L ^ (((L >> 8) & 7u) << 4);               // swizzled LDS byte
    }
    const uint32_t swz = (uint32_t)((lrow & 7) << 4);

    auto gemm_tile = [&](int g, int s) {
        const bool diag = (g == s);
        const char* aSrcF = (const char*)(feats + (size_t)g * 128 * D_DIM);
        const char* bSrcF = (const char*)(feats + (size_t)s * 128 * D_DIM);
        const uint32_t bBase = diag ? 0u : 32768u;   // diagonal: B-frags read A region

        f32x4 acc[4][4];
#pragma unroll
        for (int m = 0; m < 4; ++m)
#pragma unroll
            for (int n = 0; n < 4; ++n)
                acc[m][n] = (f32x4){0.f, 0.f, 0.f, 0.f};

        auto compute = [&]() {
#pragma unroll
            for (int ks = 0; ks < 4; ++ks) {
                bf16x8 af[4], bfr[4];
#pragma unroll
                for (int m = 0; m < 4; ++m) {
                    uint32_t row = (uint32_t)(wr * 64 + m * 16 + lrow);
                    af[m] = *(const bf16x8*)(lds + ((row * 256 + ks * 64 + khalf * 16) ^ swz));
                }
#pragma unroll
                for (int n = 0; n < 4; ++n) {
                    uint32_t row = (uint32_t)(wc * 64 + n * 16 + lrow);
                    bfr[n] = *(const bf16x8*)(lds + bBase + ((row * 256 + ks * 64 + khalf * 16) ^ swz));
                }
#pragma unroll
                for (int m = 0; m < 4; ++m)
#pragma unroll
                    for (int n = 0; n < 4; ++n)
                        acc[m][n] = MFMA(af[m], bfr[n], acc[m][n]);
            }
        };

        // ---- stage chunk 0 (A, and B if off-diag) ----
        {
            float4 fa[8][2], fb[8][2];
#pragma unroll
            for (int o = 0; o < 8; ++o) {
                const char* pa = aSrcF + LgF[o];
                fa[o][0] = *(const float4*)pa;  fa[o][1] = *(const float4*)(pa + 16);
            }
            if (!diag) {
#pragma unroll
                for (int o = 0; o < 8; ++o) {
                    const char* pb = bSrcF + LgF[o];
                    fb[o][0] = *(const float4*)pb;  fb[o][1] = *(const float4*)(pb + 16);
                }
            }
#pragma unroll
            for (int o = 0; o < 8; ++o)
                *(bf16x8*)(lds + Lw[o]) = cvt8(fa[o][0], fa[o][1]);
            if (!diag) {
#pragma unroll
                for (int o = 0; o < 8; ++o)
                    *(bf16x8*)(lds + 32768 + Lw[o]) = cvt8(fb[o][0], fb[o][1]);
            }
        }
        __syncthreads();        // chunk 0 ready (also covers histogram / prev tile)

        // ---- prefetch A chunk 1 into registers (latency hides under meta + compute 0) ----
        float4 pfa[8][2];
#pragma unroll
        for (int o = 0; o < 8; ++o) {
            const char* pa = aSrcF + LgF[o] + 512;
            pfa[o][0] = *(const float4*)pa;  pfa[o][1] = *(const float4*)(pa + 16);
        }

        // per-tile metadata: 16 anchors x 16 workers
        {
            int aIdx = tid >> 4, q = tid & 15;
            int aAnchor = (aIdx < 8) ? (g * 8 + aIdx) : (s * 8 + aIdx - 8);
            int la = labS[aAnchor];
            int rk = 0, tf = 0;
            for (int b = q; b < aAnchor; b += 16) {
                int lb = labS[b];
                rk += (lb == la);
                tf += cntS[lb];
            }
#pragma unroll
            for (int msk = 1; msk < 16; msk <<= 1) {
                rk += __shfl_xor(rk, msk, 64);
                tf += __shfl_xor(tf, msk, 64);
            }
            if (q == 0) { metaRank[aIdx] = rk; metaToff[aIdx] = tf; }
        }

        compute();              // chunk 0
        __syncthreads();        // reads of chunk 0 done

        // ---- stage chunk 1: write prefetched A; load+write B ----
#pragma unroll
        for (int o = 0; o < 8; ++o)
            *(bf16x8*)(lds + Lw[o]) = cvt8(pfa[o][0], pfa[o][1]);
        if (!diag) {
            float4 fb[8][2];
#pragma unroll
            for (int o = 0; o < 8; ++o) {
                const char* pb = bSrcF + LgF[o] + 512;
                fb[o][0] = *(const float4*)pb;  fb[o][1] = *(const float4*)(pb + 16);
            }
#pragma unroll
            for (int o = 0; o < 8; ++o)
                *(bf16x8*)(lds + 32768 + Lw[o]) = cvt8(fb[o][0], fb[o][1]);
        }
        __syncthreads();        // chunk 1 ready (meta visible)
        compute();
        __syncthreads();        // LDS free -> transpose scratch

        // ---- epilogue ----
        const int raBase = g * 8 + wr * 4, caBase = s * 8 + wc * 4;
        int labR[4], offR[4], rankR[4], labC[4], rankC[4], offC[4];
#pragma unroll
        for (int m = 0; m < 4; ++m) {
            labR[m]  = labS[raBase + m];
            offR[m]  = metaToff[wr * 4 + m];
            rankR[m] = metaRank[wr * 4 + m];
        }
#pragma unroll
        for (int n = 0; n < 4; ++n) {
            labC[n]  = labS[caBase + n];
            rankC[n] = metaRank[8 + wc * 4 + n];
            offC[n]  = metaToff[8 + wc * 4 + n];
        }

        float aAll[4][4];
        float colP[4];
#pragma unroll
        for (int m = 0; m < 4; ++m)
#pragma unroll
            for (int i = 0; i < 4; ++i) aAll[m][i] = 0.f;
#pragma unroll
        for (int n = 0; n < 4; ++n) colP[n] = 0.f;

        float* scr = (float*)lds + wid * 256;   // 1 KB per-wave transpose scratch

#pragma unroll
        for (int m = 0; m < 4; ++m) {
#pragma unroll
            for (int n = 0; n < 4; ++n) {
                f32x4 c = acc[m][n];
                float e[4];
#pragma unroll
                for (int i = 0; i < 4; ++i) {
                    e[i] = exp2f(__builtin_fmaf(c[i], K1, -K1));
                    aAll[m][i] += e[i];
                }
                if (!diag)
                    colP[n] += e[0] + e[1] + e[2] + e[3];
                if (labR[m] == labC[n]) {    // wave-uniform positive tile
                    *(f32x4*)(posBuf + (size_t)(offR[m] + rankC[n]) * 256 + lane * 4) = c;
                    if (!diag) {
#pragma unroll
                        for (int i = 0; i < 4; ++i)
                            scr[(khalf * 4 + i) * 16 + lrow] = c[i];
                        __builtin_amdgcn_s_waitcnt(0);          // wave-local LDS RAW
                        f32x4 tr = *(f32x4*)(scr + lrow * 16 + khalf * 4);
                        *(f32x4*)(posBuf + (size_t)(offC[n] + rankR[m]) * 256 + lane * 4) = tr;
                    }
                }
            }
        }

#pragma unroll
        for (int msk = 1; msk < 16; msk <<= 1)
#pragma unroll
            for (int m = 0; m < 4; ++m)
#pragma unroll
                for (int i = 0; i < 4; ++i)
                    aAll[m][i] += __shfl_xor(aAll[m][i], msk, 64);

        if (lrow == 0) {
#pragma unroll
            for (int m = 0; m < 4; ++m)
#pragma unroll
                for (int i = 0; i < 4; ++i) {
                    int row = g * 128 + wr * 64 + m * 16 + khalf * 4 + i;
                    partAll[row * NPART + s * 2 + wc] = aAll[m][i];
                }
        }

        if (!diag) {
#pragma unroll
            for (int msk = 16; msk < 64; msk <<= 1)
#pragma unroll
                for (int n = 0; n < 4; ++n)
                    colP[n] += __shfl_xor(colP[n], msk, 64);
            if (lane < 16) {
#pragma unroll
                for (int n = 0; n < 4; ++n) {
                    int row = s * 128 + wc * 64 + n * 16 + lane;
                    partAll[row * NPART + g * 2 + wr] = colP[n];
                }
            }
        }
        __syncthreads();        // scr reads done before any next-tile staging
    };

    if (blockIdx.x < NOFF) {
        // strict upper triangle (g<s), XCD-swizzled (496 = 8*62)
        int swzId = (blockIdx.x & 7) * 62 + (blockIdx.x >> 3);
        int rem = swzId, g = 0;
        while (rem >= NGRP - 1 - g) { rem -= NGRP - 1 - g; ++g; }
        gemm_tile(g, g + 1 + rem);
    } else {
        int j = blockIdx.x - NOFF;     // 0..15 -> two diagonal tiles each
        gemm_tile(2 * j, 2 * j);
        gemm_tile(2 * j + 1, 2 * j + 1);
    }
}

// ---------- kernel 2: elementwise positive pass + atomic final ----------
__global__ void __launch_bounds__(256) k_passB(const float* __restrict__ posBuf,
                                               const int* __restrict__ labels,
                                               const float* __restrict__ partAll,
                                               float* __restrict__ out) {
    int rt  = blockIdx.x;
    int tid = threadIdx.x;
    int l = tid >> 2, i = tid & 3;
    int r   = (l >> 4) * 4 + i;        // row within tile (fixed per thread)
    int col = l & 15;

    __shared__ float tile[MAXNP * 256];
    __shared__ float shA[16][17];
    __shared__ float shB[16][17];
    __shared__ float nsSh[16], PSh[16];
    __shared__ int labS[N_ANCH];
    __shared__ int cntS[32];
    __shared__ int wRk[4], wTf[4];
    __shared__ int mNp, mOff, mRank;

    // in-block metadata for anchor rt
    labS[tid] = labels[tid];
    if (tid < 32) cntS[tid] = 0;
    __syncthreads();
    atomicAdd(&cntS[labS[tid]], 1);
    __syncthreads();
    {
        int la = labS[rt];
        int rk = 0, tf = 0;
        if (tid < rt) { int lb = labS[tid]; rk = (lb == la) ? 1 : 0; tf = cntS[lb]; }
#pragma unroll
        for (int msk = 1; msk < 64; msk <<= 1) {
            rk += __shfl_xor(rk, msk, 64);
            tf += __shfl_xor(tf, msk, 64);
        }
        if ((tid & 63) == 0) { wRk[tid >> 6] = rk; wTf[tid >> 6] = tf; }
        __syncthreads();
        if (tid == 0) {
            mNp   = cntS[la];
            mRank = wRk[0] + wRk[1] + wRk[2] + wRk[3];
            mOff  = wTf[0] + wTf[1] + wTf[2] + wTf[3];
        }
        __syncthreads();
    }
    int np = mNp, off = mOff, selfRank = mRank;

    float sE = 0.f, sP = 0.f;
    const float* src = posBuf + (size_t)off * 256 + tid;
    for (int j = 0; j < np; ++j) {
        float c = src[j * 256];
        tile[j * 256 + tid] = c;
        float l2 = __builtin_fmaf(c, K1, -K1);
        sE += exp2f(l2);
        bool diag = (j == selfRank) & (col == r);
        sP += diag ? 0.f : l2;
    }
    shA[r][col] = sE;
    shB[r][col] = sP;
    __syncthreads();
    if (tid < 16) {
        float e = 0.f, p = 0.f;
#pragma unroll
        for (int cc = 0; cc < 16; ++cc) { e += shA[tid][cc]; p += shB[tid][cc]; }
        const float* pa = partAll + (size_t)(rt * 16 + tid) * NPART;
        float sall = 0.f;
#pragma unroll
        for (int q = 0; q < 16; ++q) {
            float4 v = *(const float4*)(pa + q * 4);
            sall += v.x + v.y + v.z + v.w;
        }
        nsSh[tid] = sall - e;          // negative-pair exp sum
        PSh[tid]  = p;
    }
    __syncthreads();

    float nsv = nsSh[r];
    float sL = 0.f;
    for (int j = 0; j < np; ++j) {
        float c  = tile[j * 256 + tid];
        float l2 = __builtin_fmaf(c, K1, -K1);
        float lg = __log2f(exp2f(l2) + nsv);
        bool diag = (j == selfRank) & (col == r);
        sL += diag ? 0.f : lg;
    }
    __syncthreads();
    shA[r][col] = sL;
    __syncthreads();
    if (tid < 16) {
        float L = 0.f;
#pragma unroll
        for (int cc = 0; cc < 16; ++cc) L += shA[tid][cc];
        float npRow = (float)(16 * np - 1);
        shB[0][tid] = (PSh[tid] - L) / npRow;
    }
    __syncthreads();
    if (tid == 0) {
        float sx = 0.f;
#pragma unroll
        for (int q = 0; q < 16; ++q) sx += shB[0][q];
        atomicAdd(out, -sx * (LN2 / (float)N_TOT));   // out zeroed by pass1 block 0
    }
}

extern "C" void kernel_launch(void* const* d_in, const int* in_sizes, int n_in,
                              void* d_out, int out_size, void* d_ws, size_t ws_size,
                              hipStream_t stream) {
    const float* feats  = (const float*)d_in[0];
    const int*   labels = (const int*)d_in[1];
    float* out = (float*)d_out;

    char* ws = (char*)d_ws;
    float*  partAll = (float*)(ws + (2u << 20));                    // 1 MB (4096*64 f32)
    float*  posBuf  = (float*)(ws + (3u << 20));                    // 8 MB

    k_pass1<<<NBLK, 256, 0, stream>>>(feats, labels, partAll, posBuf, out);
    k_passB<<<N_ANCH, 256, 0, stream>>>(posBuf, labels, partAll, out);
}